// Round 15
// baseline (188.283 us; speedup 1.0000x reference)
//
#include <hip/hip_runtime.h>
#include <hip/hip_bf16.h>
#include <cmath>
#include <cstddef>

// Problem constants: B=2, S=2048, D=768, H=12, Dh=64, 3D=2304.
#define B_    2
#define S_    2048
#define D_    768
#define H_    12
#define DH_   64
#define NQKV_ 2304

typedef __attribute__((ext_vector_type(8))) short  short8;   // 8 bf16 (K=32 MFMA A/B frag)
typedef __attribute__((ext_vector_type(4))) short  short4v;  // 4 bf16 (b64 store)
typedef __attribute__((ext_vector_type(4))) float  floatx4;  // MFMA C/D frag

// fp32 -> bf16 RNE via the native conversion (v_cvt_pk_bf16_f32 when paired).
__device__ __forceinline__ unsigned short f2bf(float f) {
    union { __hip_bfloat16 h; unsigned short u; } cv;
    cv.h = __float2bfloat16(f);
    return cv.u;
}

// async global->LDS 16B: wave-uniform LDS base, HW adds lane*16.
__device__ __forceinline__ void stage16(const unsigned short* g, unsigned short* ldsbase, int lane) {
#if __has_builtin(__builtin_amdgcn_global_load_lds)
    __builtin_amdgcn_global_load_lds(
        (const __attribute__((address_space(1))) unsigned int*)g,
        (__attribute__((address_space(3))) unsigned int*)ldsbase, 16, 0, 0);
#else
    *(short8*)(ldsbase + lane * 8) = *(const short8*)g;
#endif
}

// ---------------------------------------------------------------------------
// Convert x (fp32 [4096][768]) -> bf16, flat.
// ---------------------------------------------------------------------------
__global__ void cvt_x_kernel(const float* __restrict__ x, unsigned short* __restrict__ xb)
{
    int i = (blockIdx.x * 256 + threadIdx.x) * 8;
    float4 a = *(const float4*)(x + i);
    float4 b = *(const float4*)(x + i + 4);
    short8 v;
    v[0] = (short)f2bf(a.x); v[1] = (short)f2bf(a.y);
    v[2] = (short)f2bf(a.z); v[3] = (short)f2bf(a.w);
    v[4] = (short)f2bf(b.x); v[5] = (short)f2bf(b.y);
    v[6] = (short)f2bf(b.z); v[7] = (short)f2bf(b.w);
    *(short8*)(xb + i) = v;
}

// ---------------------------------------------------------------------------
// Transpose+convert W [K=768][N] fp32 -> WT [N][768] bf16. z=0: Wqkv, z=1: Wvw.
// ---------------------------------------------------------------------------
__global__ void cvt_w_kernel(const float* __restrict__ Wq, const float* __restrict__ Wv,
                             unsigned short* __restrict__ WqT, unsigned short* __restrict__ WvT)
{
    const int z = blockIdx.z;
    const int N = z ? D_ : NQKV_;
    if ((int)blockIdx.x * 32 >= N) return;
    const float* W = z ? Wv : Wq;
    unsigned short* WT = z ? WvT : WqT;

    __shared__ float t[32][33];
    const int tx = threadIdx.x, ty = threadIdx.y;
    const int n0 = blockIdx.x * 32, k0 = blockIdx.y * 32;
    #pragma unroll
    for (int i = 0; i < 4; ++i)
        t[ty + i * 8][tx] = W[(size_t)(k0 + ty + i * 8) * N + n0 + tx];
    __syncthreads();
    #pragma unroll
    for (int i = 0; i < 4; ++i)
        WT[(size_t)(n0 + ty + i * 8) * 768 + k0 + tx] = f2bf(t[tx][ty + i * 8]);
}

// ---------------------------------------------------------------------------
// Transpose V [bh][2048][64] bf16 -> VT [bh][64][2048] bf16.
// ---------------------------------------------------------------------------
__global__ void vt_kernel(const unsigned short* __restrict__ V, unsigned short* __restrict__ VT)
{
    __shared__ unsigned short t[64][72];
    const int bh = blockIdx.x, s0 = blockIdx.y * 64;
    const unsigned short* src = V + ((size_t)bh * S_ + s0) * DH_;
    const int r = threadIdx.x >> 3, c = (threadIdx.x & 7) * 8;
    #pragma unroll
    for (int it = 0; it < 2; ++it)
        *(short8*)&t[r + it * 32][c] = *(const short8*)(src + (size_t)(r + it * 32) * DH_ + c);
    __syncthreads();
    #pragma unroll
    for (int it = 0; it < 2; ++it) {
        int d = r + it * 32;
        short8 v;
        #pragma unroll
        for (int i = 0; i < 8; ++i) v[i] = (short)t[c + i][d];
        *(short8*)(VT + ((size_t)bh * DH_ + d) * S_ + s0 + c) = v;
    }
}

// ---------------------------------------------------------------------------
// QKV GEMM, m97 structure (r4-proven): 128x128 tile, BK=32, global_load_lds,
// 2-barrier K-loop, 4 waves x (4x4) MFMA. Scatters bf16 Q/K/V [B*H][S][64].
// Q is pre-scaled by (1/sqrt(Dh))*log2(e) so flash softmax is a bare exp2.
// ---------------------------------------------------------------------------
__global__ __launch_bounds__(256, 2)
void mm_qkv_kernel(const unsigned short* __restrict__ A, const unsigned short* __restrict__ BT,
                   const float* __restrict__ bias,
                   unsigned short* __restrict__ Qo, unsigned short* __restrict__ Ko,
                   unsigned short* __restrict__ Vo)
{
    __shared__ unsigned short As[128][32];
    __shared__ unsigned short Bs[128][32];
    const int tid = threadIdx.x;
    const int wid = tid >> 6, lane = tid & 63;
    const int q = lane >> 4, ln = lane & 15;
    const int wm = (wid & 1) * 64, wn = (wid >> 1) * 64;
    const int m0 = blockIdx.y * 128, n0 = blockIdx.x * 128;
    const int lrow = wid * 16 + (lane >> 2);
    const int lcol = (lane & 3) * 8;
    const unsigned short* Ag = A  + (size_t)(m0 + lrow) * 768 + lcol;
    const unsigned short* Bg = BT + (size_t)(n0 + lrow) * 768 + lcol;

    floatx4 acc[4][4] = {};
    for (int k0 = 0; k0 < 768; k0 += 32) {
        __syncthreads();
        stage16(Ag + k0,            &As[wid * 16][0],      lane);
        stage16(Ag + k0 + 64 * 768, &As[64 + wid * 16][0], lane);
        stage16(Bg + k0,            &Bs[wid * 16][0],      lane);
        stage16(Bg + k0 + 64 * 768, &Bs[64 + wid * 16][0], lane);
        __syncthreads();
        short8 af[4], bf[4];
        #pragma unroll
        for (int mt = 0; mt < 4; ++mt) af[mt] = *(const short8*)&As[wm + mt * 16 + ln][q * 8];
        #pragma unroll
        for (int nt = 0; nt < 4; ++nt) bf[nt] = *(const short8*)&Bs[wn + nt * 16 + ln][q * 8];
        #pragma unroll
        for (int mt = 0; mt < 4; ++mt)
            #pragma unroll
            for (int nt = 0; nt < 4; ++nt)
                acc[mt][nt] = __builtin_amdgcn_mfma_f32_16x16x32_bf16(af[mt], bf[nt], acc[mt][nt], 0, 0, 0);
    }

    const int t = n0 / 768;                        // 0:Q 1:K 2:V
    unsigned short* __restrict__ dst = (t == 0) ? Qo : ((t == 1) ? Ko : Vo);
    // Q pre-scale: (1/sqrt(64)) * log2(e)
    const float qscale = (t == 0) ? 0.18033688011112042f : 1.0f;
    const int colb = n0 - t * 768 + wn;
    float bv[4];
    #pragma unroll
    for (int nt = 0; nt < 4; ++nt) bv[nt] = bias[n0 + wn + nt * 16 + ln];
    #pragma unroll
    for (int mt = 0; mt < 4; ++mt)
        #pragma unroll
        for (int r = 0; r < 4; ++r) {
            int row = m0 + wm + mt * 16 + q * 4 + r;   // = b*2048 + s
            int bb = row >> 11, s = row & 2047;
            #pragma unroll
            for (int nt = 0; nt < 4; ++nt) {
                int col = colb + nt * 16 + ln;
                int h = col >> 6, d = col & 63;
                dst[((size_t)(bb * H_ + h) * S_ + s) * DH_ + d] = f2bf((acc[mt][nt][r] + bv[nt]) * qscale);
            }
        }
}

// ---------------------------------------------------------------------------
// Flash attention v20 — paired uniform blocks + 8-way key-split (flat
// occupancy at flash16's traffic and register footprint).
//   r14 post-mortem: three levers (traffic 2x, L1-sharing, exposure-halving)
//   all neutral at ~43.5 us; the remaining structural loss is the TRIANGLE:
//   time-avg occupancy 16.45% vs 37.5% at launch — half the kernel runs on
//   a drained machine (makespan integral, not per-tile cost). Fix the
//   utilization integral with zero change to per-tile anything:
//   * Block = 512 thr (8 waves) processes q64-tile (31-p) then p in two
//     sequential phases (flash8's proven phase loop): T(31-p)+T(p) = 66
//     tiles for EVERY block -> 384 uniform blocks, no tail.
//   * Per phase: 8-way key-split (t = wid, wid+8, ...) of the flash16 body
//     verbatim (o[4][4], qf[4][2], swapped S^T, b64 P-writes, bare-exp2
//     softmax, mask fast path). Chains ~8.25 tiles/wave. Traffic identical
//     to flash16 (~205 MB). VGPR ~124 (launch_bounds(512,2) caps 256).
//   * Merge: flash14's 8-way sequential LDS merge; LDS = r12/r13-proven
//     40 KB overlay (Pl[8][64][40] ushort UNION Ol[64][68]+li_s[8][64]
//     float), barrier before the overlay flips, barrier at phase end.
//   3072 waves = 3/SIMD co-resident, uniform durations, flat occupancy.
// ---------------------------------------------------------------------------
__global__ __launch_bounds__(512, 2)
void flash20_kernel(const unsigned short* __restrict__ Qg, const unsigned short* __restrict__ Kg,
                    const unsigned short* __restrict__ VTg, const int* __restrict__ mask,
                    unsigned short* __restrict__ VW)
{
    // Phase-1 LDS: Pl[8][64][40] ushort = 40960 B.
    // Phase-2 LDS: Ol[64][68] float = 17408 B + li_s[8][64] float = 2048 B.
    __shared__ __align__(16) unsigned char smem[40960];
    unsigned short (*Pl)[64][40] = (unsigned short (*)[64][40])smem;
    float (*Ol)[68]  = (float (*)[68])smem;
    float (*li_s)[64] = (float (*)[64])(smem + 17408);

    const int tid = threadIdx.x;
    const int wid = tid >> 6, lane = tid & 63;   // wid 0..7
    const int q = lane >> 4, ln = lane & 15;
    const int bh = blockIdx.x % 24;
    const int p  = blockIdx.x / 24;              // 0..15
    const int b = bh / H_, h = bh % H_;

    const unsigned short* Qb = Qg  + (size_t)bh * S_ * DH_;
    const unsigned short* Kb = Kg  + (size_t)bh * S_ * DH_;
    const unsigned short* Vt = VTg + (size_t)bh * DH_ * S_;
    const int* mb = mask + b * S_;

    for (int ph = 0; ph < 2; ++ph) {
        const int j  = ph ? p : (31 - p);        // heavy q64-tile first
        const int r0 = j * 64;
        const int T  = 2 * j + 2;                // number of 32-key tiles

        // Q B-frags (swapped): qf[rt][kk] = Q[r0 + rt*16 + ln][kk*32 + q*8 + ..]
        short8 qf[4][2];
        #pragma unroll
        for (int rt = 0; rt < 4; ++rt)
            #pragma unroll
            for (int kk = 0; kk < 2; ++kk)
                qf[rt][kk] = *(const short8*)(Qb + (size_t)(r0 + rt * 16 + ln) * DH_ + kk * 32 + q * 8);

        floatx4 o[4][4] = {};      // O acc: [row-tile][d-tile]
        float li[4] = {};          // per-lane partial row sums [rt]

        for (int t = wid; t < T; t += 8) {
            const int z0 = t * 32;

            // K A-frags: kf[zt][kk] = K[z0 + zt*16 + ln][kk*32 + q*8 + ..]
            short8 kf[2][2];
            #pragma unroll
            for (int zt = 0; zt < 2; ++zt)
                #pragma unroll
                for (int kk = 0; kk < 2; ++kk)
                    kf[zt][kk] = *(const short8*)(Kb + (size_t)(z0 + zt * 16 + ln) * DH_ + kk * 32 + q * 8);

            // V^T B-frags for PV: vb[dt] = VT[dt*16+ln][z0 + q*8 + ..]
            short8 vb[4];
            #pragma unroll
            for (int dt = 0; dt < 4; ++dt)
                vb[dt] = *(const short8*)(Vt + (size_t)(dt * 16 + ln) * S_ + z0 + q * 8);

            // mask quick-check: 64 lanes cover the 32 ints (2x redundant)
            const int mi = mb[z0 + (lane & 31)];

            // ---- S^T = K Q^T : lane holds col r=ln, rows z=q*4+rr ----
            floatx4 s[2][4] = {};   // [zt][rt]
            __builtin_amdgcn_s_setprio(1);
            #pragma unroll
            for (int zt = 0; zt < 2; ++zt)
                #pragma unroll
                for (int rt = 0; rt < 4; ++rt) {
                    s[zt][rt] = __builtin_amdgcn_mfma_f32_16x16x32_bf16(kf[zt][0], qf[rt][0], s[zt][rt], 0, 0, 0);
                    s[zt][rt] = __builtin_amdgcn_mfma_f32_16x16x32_bf16(kf[zt][1], qf[rt][1], s[zt][rt], 0, 0, 0);
                }
            __builtin_amdgcn_s_setprio(0);

            // ---- fixed-max softmax; write P rows to wave-private LDS (b64) ----
            const bool diag = (z0 + 31 > r0);
            if (__all(mi != 0) && !diag) {
                // fast path: no mask, no causal — bare exp2 (Q pre-scaled)
                #pragma unroll
                for (int zt = 0; zt < 2; ++zt)
                    #pragma unroll
                    for (int rt = 0; rt < 4; ++rt) {
                        float p0 = exp2f(s[zt][rt][0]);
                        float p1 = exp2f(s[zt][rt][1]);
                        float p2 = exp2f(s[zt][rt][2]);
                        float p3 = exp2f(s[zt][rt][3]);
                        li[rt] += (p0 + p1) + (p2 + p3);
                        short4v pk;
                        pk[0] = (short)f2bf(p0); pk[1] = (short)f2bf(p1);
                        pk[2] = (short)f2bf(p2); pk[3] = (short)f2bf(p3);
                        *(short4v*)&Pl[wid][rt * 16 + ln][zt * 16 + q * 4] = pk;
                    }
            } else {
                const int4 mA = *(const int4*)&mb[z0 + q * 4];
                const int4 mB = *(const int4*)&mb[z0 + 16 + q * 4];
                int ma[2][4];
                ma[0][0] = mA.x; ma[0][1] = mA.y; ma[0][2] = mA.z; ma[0][3] = mA.w;
                ma[1][0] = mB.x; ma[1][1] = mB.y; ma[1][2] = mB.z; ma[1][3] = mB.w;
                #pragma unroll
                for (int zt = 0; zt < 2; ++zt)
                    #pragma unroll
                    for (int rt = 0; rt < 4; ++rt) {
                        const int zb = z0 + zt * 16 + q * 4;
                        const int r  = r0 + rt * 16 + ln;
                        float pv[4];
                        #pragma unroll
                        for (int rr = 0; rr < 4; ++rr) {
                            pv[rr] = exp2f(s[zt][rt][rr]);
                            if (!ma[zt][rr] || (zb + rr > r)) pv[rr] = 0.0f;
                        }
                        li[rt] += (pv[0] + pv[1]) + (pv[2] + pv[3]);
                        short4v pk;
                        pk[0] = (short)f2bf(pv[0]); pk[1] = (short)f2bf(pv[1]);
                        pk[2] = (short)f2bf(pv[2]); pk[3] = (short)f2bf(pv[3]);
                        *(short4v*)&Pl[wid][rt * 16 + ln][zt * 16 + q * 4] = pk;
                    }
            }

            // ---- O += P V  (same-wave LDS round trip; DS pipe in-order) ----
            #pragma unroll
            for (int mt = 0; mt < 4; ++mt) {
                short8 a = *(const short8*)&Pl[wid][mt * 16 + ln][q * 8];
                __builtin_amdgcn_s_setprio(1);
                #pragma unroll
                for (int dt = 0; dt < 4; ++dt)
                    o[mt][dt] = __builtin_amdgcn_mfma_f32_16x16x32_bf16(a, vb[dt], o[mt][dt], 0, 0, 0);
                __builtin_amdgcn_s_setprio(0);
            }
        }

        // li reduce across the 4 q-groups holding the same row (lanes xor 16, 32)
        #pragma unroll
        for (int rt = 0; rt < 4; ++rt) {
            float v = li[rt];
            v += __shfl_xor(v, 16);
            v += __shfl_xor(v, 32);
            li[rt] = v;
        }

        // ---- phase boundary: all waves done with Pl before Ol/li_s overlay ----
        __syncthreads();

        if (lane < 16) {
            #pragma unroll
            for (int rt = 0; rt < 4; ++rt)
                li_s[wid][rt * 16 + lane] = li[rt];
        }

        // ---- merge the 8 wave partials in LDS (fixed max -> plain addition) ----
        #pragma unroll
        for (int w = 0; w < 8; ++w) {
            if (wid == w) {
                #pragma unroll
                for (int mt = 0; mt < 4; ++mt)
                    #pragma unroll
                    for (int r = 0; r < 4; ++r) {
                        int row = mt * 16 + q * 4 + r;
                        #pragma unroll
                        for (int dt = 0; dt < 4; ++dt) {
                            if (w == 0) Ol[row][dt * 16 + ln]  = o[mt][dt][r];
                            else        Ol[row][dt * 16 + ln] += o[mt][dt][r];
                        }
                    }
            }
            __syncthreads();
        }

        // ---- normalize + write bf16 VW [B][S][768]: 64 rows x 8 chunks ----
        {
            int row = tid >> 3, c = (tid & 7) * 8;
            float inv = 1.0f / (li_s[0][row] + li_s[1][row] + li_s[2][row] + li_s[3][row] +
                                li_s[4][row] + li_s[5][row] + li_s[6][row] + li_s[7][row]);
            short8 ov;
            #pragma unroll
            for (int i = 0; i < 8; ++i) ov[i] = (short)f2bf(Ol[row][c + i] * inv);
            *(short8*)(VW + ((size_t)b * S_ + r0 + row) * D_ + h * DH_ + c) = ov;
        }
        __syncthreads();   // protect the Pl/Ol overlay before the next phase
    }
}

// ---------------------------------------------------------------------------
// Output projection (r4-proven): 128x64 tile, BK=32, global_load_lds staging.
// ---------------------------------------------------------------------------
__global__ __launch_bounds__(256, 2)
void mm_proj_kernel(const unsigned short* __restrict__ A, const unsigned short* __restrict__ BT,
                    const float* __restrict__ bias, float* __restrict__ C)
{
    __shared__ unsigned short As[128][32];
    __shared__ unsigned short Bs[64][32];
    const int tid = threadIdx.x;
    const int wid = tid >> 6, lane = tid & 63;
    const int q = lane >> 4, ln = lane & 15;
    const int wm = (wid & 1) * 64, wn = (wid >> 1) * 32;
    const int m0 = blockIdx.y * 128, n0 = blockIdx.x * 64;
    const int lrow = wid * 16 + (lane >> 2);
    const int lcol = (lane & 3) * 8;
    const unsigned short* Ag = A  + (size_t)(m0 + lrow) * 768 + lcol;
    const unsigned short* Bg = BT + (size_t)(n0 + lrow) * 768 + lcol;

    floatx4 acc[4][2] = {};
    for (int k0 = 0; k0 < 768; k0 += 32) {
        __syncthreads();
        stage16(Ag + k0,            &As[wid * 16][0],      lane);
        stage16(Ag + k0 + 64 * 768, &As[64 + wid * 16][0], lane);
        stage16(Bg + k0,            &Bs[wid * 16][0],      lane);
        __syncthreads();
        short8 af[4], bf[2];
        #pragma unroll
        for (int mt = 0; mt < 4; ++mt) af[mt] = *(const short8*)&As[wm + mt * 16 + ln][q * 8];
        #pragma unroll
        for (int nt = 0; nt < 2; ++nt) bf[nt] = *(const short8*)&Bs[wn + nt * 16 + ln][q * 8];
        #pragma unroll
        for (int mt = 0; mt < 4; ++mt)
            #pragma unroll
            for (int nt = 0; nt < 2; ++nt)
                acc[mt][nt] = __builtin_amdgcn_mfma_f32_16x16x32_bf16(af[mt], bf[nt], acc[mt][nt], 0, 0, 0);
    }

    float bv[2];
    #pragma unroll
    for (int nt = 0; nt < 2; ++nt) bv[nt] = bias[n0 + wn + nt * 16 + ln];
    #pragma unroll
    for (int mt = 0; mt < 4; ++mt)
        #pragma unroll
        for (int r = 0; r < 4; ++r) {
            size_t row = (size_t)m0 + wm + mt * 16 + q * 4 + r;
            #pragma unroll
            for (int nt = 0; nt < 2; ++nt)
                C[row * D_ + n0 + wn + nt * 16 + ln] = acc[mt][nt][r] + bv[nt];
        }
}

// ---------------------------------------------------------------------------
extern "C" void kernel_launch(void* const* d_in, const int* in_sizes, int n_in,
                              void* d_out, int out_size, void* d_ws, size_t ws_size,
                              hipStream_t stream)
{
    (void)in_sizes; (void)n_in; (void)out_size; (void)ws_size;
    const float* x    = (const float*)d_in[0];
    const float* Wqkv = (const float*)d_in[1];
    const float* bqkv = (const float*)d_in[2];
    const float* Wvw  = (const float*)d_in[3];
    const float* bvw  = (const float*)d_in[4];
    const int*   mask = (const int*)d_in[5];
    float* out = (float*)d_out;

    // workspace carve-up (ushort units) — identical to the proven round-3 layout
    const size_t XN  = (size_t)B_ * S_ * D_;        // 3,145,728 elements
    unsigned short* ws  = (unsigned short*)d_ws;
    unsigned short* xb  = ws;                        // [4096][768] bf16
    unsigned short* WqT = xb  + XN;                  // [2304][768]
    unsigned short* WvT = WqT + (size_t)NQKV_ * D_;  // [768][768]
    unsigned short* Qb  = WvT + (size_t)D_ * D_;     // [24][2048][64]
    unsigned short* Kb  = Qb + XN;
    unsigned short* Vb  = Kb + XN;
    unsigned short* VbT = Vb + XN;                   // [24][64][2048]
    unsigned short* VW  = VbT + XN;                  // [4096][768]

    cvt_x_kernel<<<dim3(XN / (256 * 8)), 256, 0, stream>>>(x, xb);
    cvt_w_kernel<<<dim3(NQKV_ / 32, D_ / 32, 2), dim3(32, 8), 0, stream>>>(Wqkv, Wvw, WqT, WvT);
    mm_qkv_kernel<<<dim3(NQKV_ / 128, (B_ * S_) / 128), 256, 0, stream>>>(xb, WqT, bqkv, Qb, Kb, Vb);
    vt_kernel<<<dim3(B_ * H_, S_ / 64), 256, 0, stream>>>(Vb, VbT);
    flash20_kernel<<<dim3(24 * 16), 512, 0, stream>>>(Qb, Kb, VbT, mask, VW);
    mm_proj_kernel<<<dim3(D_ / 64, (B_ * S_) / 128), 256, 0, stream>>>(VW, WvT, bvw, out);
}

// Round 16
// 162.237 us; speedup vs baseline: 1.1605x; 1.1605x over previous
//
#include <hip/hip_runtime.h>
#include <hip/hip_bf16.h>
#include <cmath>
#include <cstddef>

// Problem constants: B=2, S=2048, D=768, H=12, Dh=64, 3D=2304.
#define B_    2
#define S_    2048
#define D_    768
#define H_    12
#define DH_   64
#define NQKV_ 2304

typedef __attribute__((ext_vector_type(8))) short  short8;   // 8 bf16 (K=32 MFMA A/B frag)
typedef __attribute__((ext_vector_type(4))) short  short4v;  // 4 bf16 (b64 store)
typedef __attribute__((ext_vector_type(4))) float  floatx4;  // MFMA C/D frag

// fp32 -> bf16 RNE via the native conversion (v_cvt_pk_bf16_f32 when paired).
__device__ __forceinline__ unsigned short f2bf(float f) {
    union { __hip_bfloat16 h; unsigned short u; } cv;
    cv.h = __float2bfloat16(f);
    return cv.u;
}

// async global->LDS 16B: wave-uniform LDS base, HW adds lane*16.
__device__ __forceinline__ void stage16(const unsigned short* g, unsigned short* ldsbase, int lane) {
#if __has_builtin(__builtin_amdgcn_global_load_lds)
    __builtin_amdgcn_global_load_lds(
        (const __attribute__((address_space(1))) unsigned int*)g,
        (__attribute__((address_space(3))) unsigned int*)ldsbase, 16, 0, 0);
#else
    *(short8*)(ldsbase + lane * 8) = *(const short8*)g;
#endif
}

// ---------------------------------------------------------------------------
// Convert x (fp32 [4096][768]) -> bf16, flat.
// ---------------------------------------------------------------------------
__global__ void cvt_x_kernel(const float* __restrict__ x, unsigned short* __restrict__ xb)
{
    int i = (blockIdx.x * 256 + threadIdx.x) * 8;
    float4 a = *(const float4*)(x + i);
    float4 b = *(const float4*)(x + i + 4);
    short8 v;
    v[0] = (short)f2bf(a.x); v[1] = (short)f2bf(a.y);
    v[2] = (short)f2bf(a.z); v[3] = (short)f2bf(a.w);
    v[4] = (short)f2bf(b.x); v[5] = (short)f2bf(b.y);
    v[6] = (short)f2bf(b.z); v[7] = (short)f2bf(b.w);
    *(short8*)(xb + i) = v;
}

// ---------------------------------------------------------------------------
// Transpose+convert W [K=768][N] fp32 -> WT [N][768] bf16. z=0: Wqkv, z=1: Wvw.
// ---------------------------------------------------------------------------
__global__ void cvt_w_kernel(const float* __restrict__ Wq, const float* __restrict__ Wv,
                             unsigned short* __restrict__ WqT, unsigned short* __restrict__ WvT)
{
    const int z = blockIdx.z;
    const int N = z ? D_ : NQKV_;
    if ((int)blockIdx.x * 32 >= N) return;
    const float* W = z ? Wv : Wq;
    unsigned short* WT = z ? WvT : WqT;

    __shared__ float t[32][33];
    const int tx = threadIdx.x, ty = threadIdx.y;
    const int n0 = blockIdx.x * 32, k0 = blockIdx.y * 32;
    #pragma unroll
    for (int i = 0; i < 4; ++i)
        t[ty + i * 8][tx] = W[(size_t)(k0 + ty + i * 8) * N + n0 + tx];
    __syncthreads();
    #pragma unroll
    for (int i = 0; i < 4; ++i)
        WT[(size_t)(n0 + ty + i * 8) * 768 + k0 + tx] = f2bf(t[tx][ty + i * 8]);
}

// ---------------------------------------------------------------------------
// Transpose V [bh][2048][64] bf16 -> VT [bh][64][2048] bf16.
// ---------------------------------------------------------------------------
__global__ void vt_kernel(const unsigned short* __restrict__ V, unsigned short* __restrict__ VT)
{
    __shared__ unsigned short t[64][72];
    const int bh = blockIdx.x, s0 = blockIdx.y * 64;
    const unsigned short* src = V + ((size_t)bh * S_ + s0) * DH_;
    const int r = threadIdx.x >> 3, c = (threadIdx.x & 7) * 8;
    #pragma unroll
    for (int it = 0; it < 2; ++it)
        *(short8*)&t[r + it * 32][c] = *(const short8*)(src + (size_t)(r + it * 32) * DH_ + c);
    __syncthreads();
    #pragma unroll
    for (int it = 0; it < 2; ++it) {
        int d = r + it * 32;
        short8 v;
        #pragma unroll
        for (int i = 0; i < 8; ++i) v[i] = (short)t[c + i][d];
        *(short8*)(VT + ((size_t)bh * DH_ + d) * S_ + s0 + c) = v;
    }
}

// ---------------------------------------------------------------------------
// QKV GEMM, m97 structure (r4-proven): 128x128 tile, BK=32, global_load_lds,
// 2-barrier K-loop, 4 waves x (4x4) MFMA. Scatters bf16 Q/K/V [B*H][S][64].
// Q is pre-scaled by (1/sqrt(Dh))*log2(e) so flash softmax is a bare exp2.
// ---------------------------------------------------------------------------
__global__ __launch_bounds__(256, 2)
void mm_qkv_kernel(const unsigned short* __restrict__ A, const unsigned short* __restrict__ BT,
                   const float* __restrict__ bias,
                   unsigned short* __restrict__ Qo, unsigned short* __restrict__ Ko,
                   unsigned short* __restrict__ Vo)
{
    __shared__ unsigned short As[128][32];
    __shared__ unsigned short Bs[128][32];
    const int tid = threadIdx.x;
    const int wid = tid >> 6, lane = tid & 63;
    const int q = lane >> 4, ln = lane & 15;
    const int wm = (wid & 1) * 64, wn = (wid >> 1) * 64;
    const int m0 = blockIdx.y * 128, n0 = blockIdx.x * 128;
    const int lrow = wid * 16 + (lane >> 2);
    const int lcol = (lane & 3) * 8;
    const unsigned short* Ag = A  + (size_t)(m0 + lrow) * 768 + lcol;
    const unsigned short* Bg = BT + (size_t)(n0 + lrow) * 768 + lcol;

    floatx4 acc[4][4] = {};
    for (int k0 = 0; k0 < 768; k0 += 32) {
        __syncthreads();
        stage16(Ag + k0,            &As[wid * 16][0],      lane);
        stage16(Ag + k0 + 64 * 768, &As[64 + wid * 16][0], lane);
        stage16(Bg + k0,            &Bs[wid * 16][0],      lane);
        stage16(Bg + k0 + 64 * 768, &Bs[64 + wid * 16][0], lane);
        __syncthreads();
        short8 af[4], bf[4];
        #pragma unroll
        for (int mt = 0; mt < 4; ++mt) af[mt] = *(const short8*)&As[wm + mt * 16 + ln][q * 8];
        #pragma unroll
        for (int nt = 0; nt < 4; ++nt) bf[nt] = *(const short8*)&Bs[wn + nt * 16 + ln][q * 8];
        #pragma unroll
        for (int mt = 0; mt < 4; ++mt)
            #pragma unroll
            for (int nt = 0; nt < 4; ++nt)
                acc[mt][nt] = __builtin_amdgcn_mfma_f32_16x16x32_bf16(af[mt], bf[nt], acc[mt][nt], 0, 0, 0);
    }

    const int t = n0 / 768;                        // 0:Q 1:K 2:V
    unsigned short* __restrict__ dst = (t == 0) ? Qo : ((t == 1) ? Ko : Vo);
    // Q pre-scale: (1/sqrt(64)) * log2(e)
    const float qscale = (t == 0) ? 0.18033688011112042f : 1.0f;
    const int colb = n0 - t * 768 + wn;
    float bv[4];
    #pragma unroll
    for (int nt = 0; nt < 4; ++nt) bv[nt] = bias[n0 + wn + nt * 16 + ln];
    #pragma unroll
    for (int mt = 0; mt < 4; ++mt)
        #pragma unroll
        for (int r = 0; r < 4; ++r) {
            int row = m0 + wm + mt * 16 + q * 4 + r;   // = b*2048 + s
            int bb = row >> 11, s = row & 2047;
            #pragma unroll
            for (int nt = 0; nt < 4; ++nt) {
                int col = colb + nt * 16 + ln;
                int h = col >> 6, d = col & 63;
                dst[((size_t)(bb * H_ + h) * S_ + s) * DH_ + d] = f2bf((acc[mt][nt][r] + bv[nt]) * qscale);
            }
        }
}

// ---------------------------------------------------------------------------
// Flash attention v16 (r10-proven BEST, reverted to verbatim) — 64 q-rows
// per wave: 2x K/V traffic amortization in the proven flash9/14 geometry.
//   Final state of the session: this configuration measured the best total
//   (163.7 us, r10). Subsequent variants — traffic/4 (r13), exposure/2
//   (r14), per-wave x2 (r12, spilled), uniform pairing (r15, regressed) —
//   were all neutral-or-worse: flash is pinned at ~43.5 us by a per-tile
//   active cost insensitive to organization and invisible to the available
//   counters. Locking in the best-known kernel.
//   * Wave = 64 q-rows (qf x4 row-tiles, o[4][4]); Bc=32 key-split x4
//     across 4 waves (t = wid, wid+4, ...): K/V traffic ~205 MB.
//   * Critical chain: heaviest q64-tile = 16 serial tiles. No in-loop
//     barriers. Merge: fixed-max plain-sum 4-way LDS merge over 64 rows.
//   * Swapped S^T, b64 P-writes, bare-exp2 softmax w/ pre-scaled Q,
//     mask fast path, setprio around MFMA clusters.
//   Grid 24 bh x 32 q64-tiles = 768 blocks x 256 thr, heavy-first.
// ---------------------------------------------------------------------------
__global__ __launch_bounds__(256, 2)
void flash16_kernel(const unsigned short* __restrict__ Qg, const unsigned short* __restrict__ Kg,
                    const unsigned short* __restrict__ VTg, const int* __restrict__ mask,
                    unsigned short* __restrict__ VW)
{
    __shared__ unsigned short Pl[4][64][40];  // per-wave P rows [r][z] (stride 80B)
    __shared__ float Ol[64][68];              // merged O
    __shared__ float li_s[4][64];             // per-wave row sums

    const int tid = threadIdx.x;
    const int wid = tid >> 6, lane = tid & 63;
    const int q = lane >> 4, ln = lane & 15;
    const int bh = blockIdx.x % 24;
    const int j  = 31 - blockIdx.x / 24;      // heavy q64-tiles first
    const int b = bh / H_, h = bh % H_;
    const int r0 = j * 64;

    const unsigned short* Qb = Qg  + (size_t)bh * S_ * DH_;
    const unsigned short* Kb = Kg  + (size_t)bh * S_ * DH_;
    const unsigned short* Vt = VTg + (size_t)bh * DH_ * S_;
    const int* mb = mask + b * S_;

    // Q B-frags (swapped): qf[rt][kk] = Q[r0 + rt*16 + ln][kk*32 + q*8 + ..]
    short8 qf[4][2];
    #pragma unroll
    for (int rt = 0; rt < 4; ++rt)
        #pragma unroll
        for (int kk = 0; kk < 2; ++kk)
            qf[rt][kk] = *(const short8*)(Qb + (size_t)(r0 + rt * 16 + ln) * DH_ + kk * 32 + q * 8);

    floatx4 o[4][4] = {};      // O acc: [row-tile][d-tile]
    float li[4] = {};          // per-lane partial row sums [rt]
    const int T = 2 * j + 2;   // number of 32-key tiles

    for (int t = wid; t < T; t += 4) {
        const int z0 = t * 32;

        // K A-frags: kf[zt][kk] = K[z0 + zt*16 + ln][kk*32 + q*8 + ..]
        short8 kf[2][2];
        #pragma unroll
        for (int zt = 0; zt < 2; ++zt)
            #pragma unroll
            for (int kk = 0; kk < 2; ++kk)
                kf[zt][kk] = *(const short8*)(Kb + (size_t)(z0 + zt * 16 + ln) * DH_ + kk * 32 + q * 8);

        // V^T B-frags for PV: vb[dt] = VT[dt*16+ln][z0 + q*8 + ..]
        short8 vb[4];
        #pragma unroll
        for (int dt = 0; dt < 4; ++dt)
            vb[dt] = *(const short8*)(Vt + (size_t)(dt * 16 + ln) * S_ + z0 + q * 8);

        // mask quick-check: 64 lanes cover the 32 ints (2x redundant)
        const int mi = mb[z0 + (lane & 31)];

        // ---- S^T = K Q^T : lane holds col r=ln, rows z=q*4+rr ----
        floatx4 s[2][4] = {};   // [zt][rt]
        __builtin_amdgcn_s_setprio(1);
        #pragma unroll
        for (int zt = 0; zt < 2; ++zt)
            #pragma unroll
            for (int rt = 0; rt < 4; ++rt) {
                s[zt][rt] = __builtin_amdgcn_mfma_f32_16x16x32_bf16(kf[zt][0], qf[rt][0], s[zt][rt], 0, 0, 0);
                s[zt][rt] = __builtin_amdgcn_mfma_f32_16x16x32_bf16(kf[zt][1], qf[rt][1], s[zt][rt], 0, 0, 0);
            }
        __builtin_amdgcn_s_setprio(0);

        // ---- fixed-max softmax; write P rows to wave-private LDS (b64) ----
        const bool diag = (z0 + 31 > r0);
        if (__all(mi != 0) && !diag) {
            // fast path: no mask, no causal — bare exp2 (Q pre-scaled)
            #pragma unroll
            for (int zt = 0; zt < 2; ++zt)
                #pragma unroll
                for (int rt = 0; rt < 4; ++rt) {
                    float p0 = exp2f(s[zt][rt][0]);
                    float p1 = exp2f(s[zt][rt][1]);
                    float p2 = exp2f(s[zt][rt][2]);
                    float p3 = exp2f(s[zt][rt][3]);
                    li[rt] += (p0 + p1) + (p2 + p3);
                    short4v pk;
                    pk[0] = (short)f2bf(p0); pk[1] = (short)f2bf(p1);
                    pk[2] = (short)f2bf(p2); pk[3] = (short)f2bf(p3);
                    *(short4v*)&Pl[wid][rt * 16 + ln][zt * 16 + q * 4] = pk;
                }
        } else {
            const int4 mA = *(const int4*)&mb[z0 + q * 4];
            const int4 mB = *(const int4*)&mb[z0 + 16 + q * 4];
            int ma[2][4];
            ma[0][0] = mA.x; ma[0][1] = mA.y; ma[0][2] = mA.z; ma[0][3] = mA.w;
            ma[1][0] = mB.x; ma[1][1] = mB.y; ma[1][2] = mB.z; ma[1][3] = mB.w;
            #pragma unroll
            for (int zt = 0; zt < 2; ++zt)
                #pragma unroll
                for (int rt = 0; rt < 4; ++rt) {
                    const int zb = z0 + zt * 16 + q * 4;
                    const int r  = r0 + rt * 16 + ln;
                    float p[4];
                    #pragma unroll
                    for (int rr = 0; rr < 4; ++rr) {
                        p[rr] = exp2f(s[zt][rt][rr]);
                        if (!ma[zt][rr] || (zb + rr > r)) p[rr] = 0.0f;
                    }
                    li[rt] += (p[0] + p[1]) + (p[2] + p[3]);
                    short4v pk;
                    pk[0] = (short)f2bf(p[0]); pk[1] = (short)f2bf(p[1]);
                    pk[2] = (short)f2bf(p[2]); pk[3] = (short)f2bf(p[3]);
                    *(short4v*)&Pl[wid][rt * 16 + ln][zt * 16 + q * 4] = pk;
                }
        }

        // ---- O += P V  (same-wave LDS round trip; DS pipe in-order) ----
        #pragma unroll
        for (int mt = 0; mt < 4; ++mt) {
            short8 a = *(const short8*)&Pl[wid][mt * 16 + ln][q * 8];
            __builtin_amdgcn_s_setprio(1);
            #pragma unroll
            for (int dt = 0; dt < 4; ++dt)
                o[mt][dt] = __builtin_amdgcn_mfma_f32_16x16x32_bf16(a, vb[dt], o[mt][dt], 0, 0, 0);
            __builtin_amdgcn_s_setprio(0);
        }
    }

    // li reduce across the 4 q-groups holding the same row (lanes xor 16, 32)
    #pragma unroll
    for (int rt = 0; rt < 4; ++rt) {
        float v = li[rt];
        v += __shfl_xor(v, 16);
        v += __shfl_xor(v, 32);
        li[rt] = v;
    }
    if (lane < 16) {
        #pragma unroll
        for (int rt = 0; rt < 4; ++rt)
            li_s[wid][rt * 16 + lane] = li[rt];
    }

    // ---- merge the 4 wave partials in LDS (fixed max -> plain addition) ----
    #pragma unroll
    for (int w = 0; w < 4; ++w) {
        if (wid == w) {
            #pragma unroll
            for (int mt = 0; mt < 4; ++mt)
                #pragma unroll
                for (int r = 0; r < 4; ++r) {
                    int row = mt * 16 + q * 4 + r;
                    #pragma unroll
                    for (int dt = 0; dt < 4; ++dt) {
                        if (w == 0) Ol[row][dt * 16 + ln]  = o[mt][dt][r];
                        else        Ol[row][dt * 16 + ln] += o[mt][dt][r];
                    }
                }
        }
        __syncthreads();
    }

    // ---- normalize + write bf16 VW [B][S][768]: 64 rows x 8 chunks ----
    #pragma unroll
    for (int it = 0; it < 2; ++it) {
        int idx = tid + it * 256;
        int row = idx >> 3, c = (idx & 7) * 8;
        float inv = 1.0f / (li_s[0][row] + li_s[1][row] + li_s[2][row] + li_s[3][row]);
        short8 ov;
        #pragma unroll
        for (int i = 0; i < 8; ++i) ov[i] = (short)f2bf(Ol[row][c + i] * inv);
        *(short8*)(VW + ((size_t)b * S_ + r0 + row) * D_ + h * DH_ + c) = ov;
    }
}

// ---------------------------------------------------------------------------
// Output projection (r4-proven): 128x64 tile, BK=32, global_load_lds staging.
// ---------------------------------------------------------------------------
__global__ __launch_bounds__(256, 2)
void mm_proj_kernel(const unsigned short* __restrict__ A, const unsigned short* __restrict__ BT,
                    const float* __restrict__ bias, float* __restrict__ C)
{
    __shared__ unsigned short As[128][32];
    __shared__ unsigned short Bs[64][32];
    const int tid = threadIdx.x;
    const int wid = tid >> 6, lane = tid & 63;
    const int q = lane >> 4, ln = lane & 15;
    const int wm = (wid & 1) * 64, wn = (wid >> 1) * 32;
    const int m0 = blockIdx.y * 128, n0 = blockIdx.x * 64;
    const int lrow = wid * 16 + (lane >> 2);
    const int lcol = (lane & 3) * 8;
    const unsigned short* Ag = A  + (size_t)(m0 + lrow) * 768 + lcol;
    const unsigned short* Bg = BT + (size_t)(n0 + lrow) * 768 + lcol;

    floatx4 acc[4][2] = {};
    for (int k0 = 0; k0 < 768; k0 += 32) {
        __syncthreads();
        stage16(Ag + k0,            &As[wid * 16][0],      lane);
        stage16(Ag + k0 + 64 * 768, &As[64 + wid * 16][0], lane);
        stage16(Bg + k0,            &Bs[wid * 16][0],      lane);
        __syncthreads();
        short8 af[4], bf[2];
        #pragma unroll
        for (int mt = 0; mt < 4; ++mt) af[mt] = *(const short8*)&As[wm + mt * 16 + ln][q * 8];
        #pragma unroll
        for (int nt = 0; nt < 2; ++nt) bf[nt] = *(const short8*)&Bs[wn + nt * 16 + ln][q * 8];
        #pragma unroll
        for (int mt = 0; mt < 4; ++mt)
            #pragma unroll
            for (int nt = 0; nt < 2; ++nt)
                acc[mt][nt] = __builtin_amdgcn_mfma_f32_16x16x32_bf16(af[mt], bf[nt], acc[mt][nt], 0, 0, 0);
    }

    float bv[2];
    #pragma unroll
    for (int nt = 0; nt < 2; ++nt) bv[nt] = bias[n0 + wn + nt * 16 + ln];
    #pragma unroll
    for (int mt = 0; mt < 4; ++mt)
        #pragma unroll
        for (int r = 0; r < 4; ++r) {
            size_t row = (size_t)m0 + wm + mt * 16 + q * 4 + r;
            #pragma unroll
            for (int nt = 0; nt < 2; ++nt)
                C[row * D_ + n0 + wn + nt * 16 + ln] = acc[mt][nt][r] + bv[nt];
        }
}

// ---------------------------------------------------------------------------
extern "C" void kernel_launch(void* const* d_in, const int* in_sizes, int n_in,
                              void* d_out, int out_size, void* d_ws, size_t ws_size,
                              hipStream_t stream)
{
    (void)in_sizes; (void)n_in; (void)out_size; (void)ws_size;
    const float* x    = (const float*)d_in[0];
    const float* Wqkv = (const float*)d_in[1];
    const float* bqkv = (const float*)d_in[2];
    const float* Wvw  = (const float*)d_in[3];
    const float* bvw  = (const float*)d_in[4];
    const int*   mask = (const int*)d_in[5];
    float* out = (float*)d_out;

    // workspace carve-up (ushort units) — identical to the proven round-3 layout
    const size_t XN  = (size_t)B_ * S_ * D_;        // 3,145,728 elements
    unsigned short* ws  = (unsigned short*)d_ws;
    unsigned short* xb  = ws;                        // [4096][768] bf16
    unsigned short* WqT = xb  + XN;                  // [2304][768]
    unsigned short* WvT = WqT + (size_t)NQKV_ * D_;  // [768][768]
    unsigned short* Qb  = WvT + (size_t)D_ * D_;     // [24][2048][64]
    unsigned short* Kb  = Qb + XN;
    unsigned short* Vb  = Kb + XN;
    unsigned short* VbT = Vb + XN;                   // [24][64][2048]
    unsigned short* VW  = VbT + XN;                  // [4096][768]

    cvt_x_kernel<<<dim3(XN / (256 * 8)), 256, 0, stream>>>(x, xb);
    cvt_w_kernel<<<dim3(NQKV_ / 32, D_ / 32, 2), dim3(32, 8), 0, stream>>>(Wqkv, Wvw, WqT, WvT);
    mm_qkv_kernel<<<dim3(NQKV_ / 128, (B_ * S_) / 128), 256, 0, stream>>>(xb, WqT, bqkv, Qb, Kb, Vb);
    vt_kernel<<<dim3(B_ * H_, S_ / 64), 256, 0, stream>>>(Vb, VbT);
    flash16_kernel<<<dim3(24 * 32), 256, 0, stream>>>(Qb, Kb, VbT, mask, VW);
    mm_proj_kernel<<<dim3(D_ / 64, (B_ * S_) / 128), 256, 0, stream>>>(VW, WvT, bvw, out);
}